// Round 13
// baseline (435.319 us; speedup 1.0000x reference)
//
#include <hip/hip_runtime.h>
#include <hip/hip_bf16.h>
#include <stdint.h>

#define THREADS 256
#define WB 256            // nodes per bucket
#define MAXNB 512         // max buckets
#define NBLK_A 512        // blocks in bucketing phase
#define ECAP 64           // staged edges per node (LDS)

typedef unsigned short u16;
typedef unsigned int u32;
using frag_ab = __attribute__((ext_vector_type(8))) short;   // 8 bf16 (4 VGPR)
using f32x4  = __attribute__((ext_vector_type(4))) float;    // 4 fp32 acc

static __host__ __device__ inline int imin(int a, int b) { return a < b ? a : b; }

static __device__ inline u16 f2b(float f) {               // f32 -> bf16 RNE
    u32 u = __builtin_bit_cast(u32, f);
    return (u16)((u + 0x7FFFu + ((u >> 16) & 1u)) >> 16);
}
static __device__ inline float b2f_lo(u32 v) { return __builtin_bit_cast(float, v << 16); }
static __device__ inline float b2f_hi(u32 v) { return __builtin_bit_cast(float, v & 0xFFFF0000u); }

// exact-formula tanh via HW exp2/rcp: rel err ~1e-6, correct at +-inf, NaN-free
static __device__ inline float tanh_fast(float x) {
    const float e = __builtin_amdgcn_exp2f(x * 2.8853900817779268f);  // 2*log2(e)
    return 1.0f - 2.0f * __builtin_amdgcn_rcpf(e + 1.0f);
}

static __device__ inline void fma8(float* a, float w, uint4 v) {
    a[0] = fmaf(w, b2f_lo(v.x), a[0]); a[1] = fmaf(w, b2f_hi(v.x), a[1]);
    a[2] = fmaf(w, b2f_lo(v.y), a[2]); a[3] = fmaf(w, b2f_hi(v.y), a[3]);
    a[4] = fmaf(w, b2f_lo(v.z), a[4]); a[5] = fmaf(w, b2f_hi(v.z), a[5]);
    a[6] = fmaf(w, b2f_lo(v.w), a[6]); a[7] = fmaf(w, b2f_hi(v.w), a[7]);
}

// per-block int64-vs-int32 detection (int64 => sampled high words all zero)
static __device__ inline bool detect64(const int* raw) {
    __shared__ int s64;
    if (threadIdx.x == 0) s64 = 1;
    __syncthreads();
    if (raw[2 * threadIdx.x + 1] != 0) s64 = 0;   // benign race
    __syncthreads();
    return s64 != 0;
}

// ---------------- A1: per-block bucket histogram (LDS atomics only) ----------------
__global__ __launch_bounds__(256)
void k_bucket_count(const int* __restrict__ raw, int E, int EPB, int NB,
                    int* __restrict__ counts) {
    const bool is64 = detect64(raw);
    __shared__ int cnt[MAXNB];
    const int t = threadIdx.x, blk = blockIdx.x;
    for (int i = t; i < NB; i += THREADS) cnt[i] = 0;
    __syncthreads();
    const int e0 = blk * EPB, e1 = imin(E, e0 + EPB);
    for (int e = e0 + t; e < e1; e += THREADS) {
        const int d = is64 ? raw[2 * E + 2 * e] : raw[E + e];
        atomicAdd(&cnt[d >> 8], 1);   // WB = 256
    }
    __syncthreads();
    for (int i = t; i < NB; i += THREADS) counts[i * NBLK_A + blk] = cnt[i];
}

// ---------------- chunked exclusive scan over counts[L] (in-place) ----------------
__global__ void k_chunk_sums(const int* __restrict__ a, int* __restrict__ chunkSum, int L) {
    __shared__ int sm[THREADS];
    const int base = blockIdx.x * 2048 + threadIdx.x * 8;
    int s = 0;
#pragma unroll
    for (int i = 0; i < 8; ++i) { int idx = base + i; if (idx < L) s += a[idx]; }
    sm[threadIdx.x] = s;
    __syncthreads();
    for (int off = THREADS / 2; off > 0; off >>= 1) {
        if (threadIdx.x < off) sm[threadIdx.x] += sm[threadIdx.x + off];
        __syncthreads();
    }
    if (threadIdx.x == 0) chunkSum[blockIdx.x] = sm[0];
}

__global__ void k_scan_offsets(const int* __restrict__ chunkSum, int* __restrict__ chunkOff,
                               int nChunks) {
    if (blockIdx.x == 0 && threadIdx.x == 0) {
        int run = 0;
        for (int i = 0; i < nChunks; ++i) { chunkOff[i] = run; run += chunkSum[i]; }
    }
}

__global__ void k_scan_write(int* __restrict__ a, const int* __restrict__ chunkOff, int L) {
    __shared__ int sm[THREADS];
    const int tid = threadIdx.x;
    const int base = blockIdx.x * 2048 + tid * 8;
    int v[8]; int s = 0;
#pragma unroll
    for (int i = 0; i < 8; ++i) { int idx = base + i; v[i] = (idx < L) ? a[idx] : 0; s += v[i]; }
    const int mysum = s;
    sm[tid] = s;
    __syncthreads();
    for (int off = 1; off < THREADS; off <<= 1) {
        int t = (tid >= off) ? sm[tid - off] : 0;
        __syncthreads();
        sm[tid] += t;
        __syncthreads();
    }
    int run = chunkOff[blockIdx.x] + sm[tid] - mysum;  // exclusive prefix
#pragma unroll
    for (int i = 0; i < 8; ++i) {
        int idx = base + i;
        if (idx < L) { a[idx] = run; run += v[i]; }
    }
}

// -------- A3: scatter packed (src | dlocal<<24) into bucket regions (4B/edge) --------
__global__ __launch_bounds__(256)
void k_bucket_scatter(const int* __restrict__ raw, int E, int EPB, int NB,
                      const int* __restrict__ offs, u32* __restrict__ pairs) {
    const bool is64 = detect64(raw);
    __shared__ int cur[MAXNB];
    const int t = threadIdx.x, blk = blockIdx.x;
    for (int i = t; i < NB; i += THREADS) cur[i] = offs[i * NBLK_A + blk];
    __syncthreads();
    const int e0 = blk * EPB, e1 = imin(E, e0 + EPB);
    for (int e = e0 + t; e < e1; e += THREADS) {
        int s, d;
        if (is64) { s = raw[2 * e]; d = raw[2 * E + 2 * e]; }
        else      { s = raw[e];     d = raw[E + e]; }
        const int p = atomicAdd(&cur[d >> 8], 1);
        pairs[p] = (u32)s | ((u32)(d & 255) << 24);    // requires N < 2^24
    }
}

// ---- B: per-bucket CSR build (deg/dinv/rowptr/csr_src), direct node order ----
__global__ __launch_bounds__(256)
void k_build(const u32* __restrict__ pairs, const int* __restrict__ offs,
             int* __restrict__ rowptr, int* __restrict__ csr_src,
             float* __restrict__ dinv, int N, int NB, int E) {
    __shared__ int deg[WB];
    __shared__ int ptr[WB];
    __shared__ int cur[WB];
    const int k = blockIdx.x, t = threadIdx.x;
    const int base = offs[k * NBLK_A];
    const int end  = (k + 1 < NB) ? offs[(k + 1) * NBLK_A] : E;
    const int n0 = k * WB;
    deg[t] = 0;
    __syncthreads();
    for (int e = base + t; e < end; e += THREADS)
        atomicAdd(&deg[pairs[e] >> 24], 1);
    __syncthreads();
    const int dv = deg[t];
    if (n0 + t < N) dinv[n0 + t] = rsqrtf((float)dv + 1.0f);
    ptr[t] = dv;
    __syncthreads();
    for (int off = 1; off < THREADS; off <<= 1) {
        int v = (t >= off) ? ptr[t - off] : 0;
        __syncthreads();
        ptr[t] += v;
        __syncthreads();
    }
    const int excl = ptr[t] - dv;
    if (n0 + t < N) rowptr[n0 + t] = base + excl;
    if (k == NB - 1 && t == 0) rowptr[N] = E;
    cur[t] = base + excl;
    __syncthreads();
    for (int e = base + t; e < end; e += THREADS) {
        const u32 w = pairs[e];
        const int p = atomicAdd(&cur[w >> 24], 1);
        csr_src[p] = (int)(w & 0xFFFFFF);
    }
}

// ---- fused: csrW[e] = {src, dinv[src]}  (blocks < WFB)  +  Xh0 = bf16(tanh(x)) ----
__global__ void k_wfill_tanh(const int* __restrict__ csr_src, const float* __restrict__ dinv,
                             uint2* __restrict__ csrW, int E,
                             const float* __restrict__ x, u16* __restrict__ Xh,
                             long long n4, int WFB) {
    if ((int)blockIdx.x < WFB) {
        int i = blockIdx.x * blockDim.x + threadIdx.x;
        const int st = WFB * blockDim.x;
        for (; i < E; i += st) {
            const int s = csr_src[i];
            csrW[i] = make_uint2((u32)s, __builtin_bit_cast(u32, dinv[s]));
        }
    } else {
        long long i = (long long)(blockIdx.x - WFB) * blockDim.x + threadIdx.x;
        const long long st = (long long)(gridDim.x - WFB) * blockDim.x;
        for (; i < n4; i += st) {
            float4 v = ((const float4*)x)[i];
            u32 lo = f2b(tanh_fast(v.x)) | ((u32)f2b(tanh_fast(v.y)) << 16);
            u32 hi = f2b(tanh_fast(v.z)) | ((u32)f2b(tanh_fast(v.w)) << 16);
            ((uint2*)Xh)[i] = make_uint2(lo, hi);
        }
    }
}

// ---- Bt: 128 rows x 512 B, PRE-SWIZZLED image of [W ; -(W@Wres)] col-major ----
__global__ void k_w2(const float* __restrict__ W, const float* __restrict__ Wres,
                     const float* __restrict__ b, const float* __restrict__ bres,
                     u16* __restrict__ Bt, float* __restrict__ cvec) {
    const int gid = blockIdx.x * blockDim.x + threadIdx.x;
    if (gid < 128 * 128) {
        const int i = gid >> 7, n = gid & 127;   // i = K row of W2, n = output col
        float s = 0.f;
#pragma unroll 8
        for (int k = 0; k < 128; ++k) s += W[i * 128 + k] * Wres[k * 128 + n];
        char* base = (char*)Bt;
        const int bh = i * 2;                    // byte within 256B half-row
        const int sb = ((bh & ~15) ^ ((n & 7) << 4)) | (bh & 15);
        *(u16*)(base + n * 512 + 256 + sb) = f2b(-s);              // W2n half
        *(u16*)(base + n * 512 + sb)       = f2b(W[i * 128 + n]);  // W half
    }
    if (gid < 128) cvec[gid] = b[gid] - bres[gid];
}

// ------- Ph = bf16(dinv[d]*(Σ w_s·Xh[s] + dinv[d]·Xh[d])) -------
// 2 nodes per quarter, jointly iterated with zero-weight padding: quarter trip
// count = max(degA,degB) (vs wave-max before) -> less issue-slot waste; 32
// nodes/block. cws leading dim padded +1 to break 4-way quarter bank alias.
__global__ __launch_bounds__(256)
void k_agg(const u16* __restrict__ Xh, const int* __restrict__ rowptr,
           const uint2* __restrict__ csrW, u16* __restrict__ Ph, int N) {
    __shared__ uint2 cws[32][ECAP + 1];        // ~16.25 KB, +1 anti-alias pad
    const int qid = threadIdx.x >> 4;          // 0..15
    const int l16 = threadIdx.x & 15;
    const int nA = blockIdx.x * 32 + qid * 2;
    const int nB = nA + 1;
    const bool vA = nA < N, vB = nB < N;
    const int c8 = l16 * 8;
    int e0A = 0, e1A = 0, e0B = 0, e1B = 0;
    if (vA) { e0A = rowptr[nA]; e1A = rowptr[nA + 1]; }
    if (vB) { e0B = rowptr[nB]; e1B = rowptr[nB + 1]; }
    const int degA = e1A - e0A, degB = e1B - e0B;
    const int nsA = degA < ECAP ? degA : ECAP;
    const int nsB = degB < ECAP ? degB : ECAP;
    const int jp = (((nsA > nsB) ? nsA : nsB) + 1) & ~1;   // pad to even, <= ECAP
    uint2* rowA = cws[qid * 2];
    uint2* rowB = cws[qid * 2 + 1];
    for (int j = l16; j < nsA; j += 16) rowA[j] = csrW[e0A + j];
    for (int j = l16; j < nsB; j += 16) rowB[j] = csrW[e0B + j];
    const uint2 padA = make_uint2((u32)(vA ? nA : 0), 0u);   // weight 0.0 => no-op FMA
    const uint2 padB = make_uint2((u32)(vB ? nB : 0), 0u);
    for (int j = nsA + l16; j < jp; j += 16) rowA[j] = padA;
    for (int j = nsB + l16; j < jp; j += 16) rowB[j] = padB;
    const float dnA = rsqrtf((float)degA + 1.0f);
    const float dnB = rsqrtf((float)degB + 1.0f);
    float accA[8] = {0.f, 0.f, 0.f, 0.f, 0.f, 0.f, 0.f, 0.f};
    float accB[8] = {0.f, 0.f, 0.f, 0.f, 0.f, 0.f, 0.f, 0.f};
    if (vA) {                                  // self-loop terms
        const uint4 v = *(const uint4*)&Xh[(size_t)nA * 128 + c8];
        fma8(accA, dnA, v);
    }
    if (vB) {
        const uint4 v = *(const uint4*)&Xh[(size_t)nB * 128 + c8];
        fma8(accB, dnB, v);
    }
    for (int j = 0; j < jp; j += 2) {          // uniform, branch-free joint loop
        const uint2 a0 = rowA[j], a1 = rowA[j + 1];
        const uint2 b0 = rowB[j], b1 = rowB[j + 1];
        const uint4 va0 = *(const uint4*)&Xh[(size_t)a0.x * 128 + c8];
        const uint4 va1 = *(const uint4*)&Xh[(size_t)a1.x * 128 + c8];
        const uint4 vb0 = *(const uint4*)&Xh[(size_t)b0.x * 128 + c8];
        const uint4 vb1 = *(const uint4*)&Xh[(size_t)b1.x * 128 + c8];
        fma8(accA, __builtin_bit_cast(float, a0.y), va0);
        fma8(accA, __builtin_bit_cast(float, a1.y), va1);
        fma8(accB, __builtin_bit_cast(float, b0.y), vb0);
        fma8(accB, __builtin_bit_cast(float, b1.y), vb1);
    }
    for (int e = e0A + ECAP; e < e1A; ++e) {   // overflow fallback (deg > ECAP), rare
        const uint2 cw = csrW[e];
        const uint4 v = *(const uint4*)&Xh[(size_t)cw.x * 128 + c8];
        fma8(accA, __builtin_bit_cast(float, cw.y), v);
    }
    for (int e = e0B + ECAP; e < e1B; ++e) {
        const uint2 cw = csrW[e];
        const uint4 v = *(const uint4*)&Xh[(size_t)cw.x * 128 + c8];
        fma8(accB, __builtin_bit_cast(float, cw.y), v);
    }
    if (vA) {
        u32 w0 = (u32)f2b(accA[0] * dnA) | ((u32)f2b(accA[1] * dnA) << 16);
        u32 w1 = (u32)f2b(accA[2] * dnA) | ((u32)f2b(accA[3] * dnA) << 16);
        u32 w2 = (u32)f2b(accA[4] * dnA) | ((u32)f2b(accA[5] * dnA) << 16);
        u32 w3 = (u32)f2b(accA[6] * dnA) | ((u32)f2b(accA[7] * dnA) << 16);
        *(uint4*)&Ph[(size_t)nA * 128 + c8] = make_uint4(w0, w1, w2, w3);
    }
    if (vB) {
        u32 w0 = (u32)f2b(accB[0] * dnB) | ((u32)f2b(accB[1] * dnB) << 16);
        u32 w1 = (u32)f2b(accB[2] * dnB) | ((u32)f2b(accB[3] * dnB) << 16);
        u32 w2 = (u32)f2b(accB[4] * dnB) | ((u32)f2b(accB[5] * dnB) << 16);
        u32 w3 = (u32)f2b(accB[6] * dnB) | ((u32)f2b(accB[7] * dnB) << 16);
        *(uint4*)&Ph[(size_t)nB * 128 + c8] = make_uint4(w0, w1, w2, w3);
    }
}

// -------- Xh = bf16(tanh([Ph|Xh] @ Bt^T + cvec)); fp32 out on last layer ----
// split-K; Bt pre-swizzled in global -> staged LINEARLY via global_load_lds;
// per-half A-frags (half0 Ph only, half1 Xh only).
__global__ __launch_bounds__(256)
void k_gemm_mfma(const u16* __restrict__ Ph, const u16* __restrict__ Xh,
                 const u16* __restrict__ Bt, const float* __restrict__ cvec,
                 float* __restrict__ Xout, u16* __restrict__ XhOut, int M, int writeF32) {
    __shared__ u16 Bs[128 * 128];     // 32 KB
    const int tid = threadIdx.x;
    const int wid = tid >> 6, lane = tid & 63;
    const int rowbase = blockIdx.x * 128 + wid * 32;
    const int rl = lane & 15;
    const int kg = (lane >> 4) * 8;

    const int r0 = rowbase + rl;
    const size_t ar0 = (size_t)((r0      < M) ? r0      : M - 1);
    const size_t ar1 = (size_t)((r0 + 16 < M) ? r0 + 16 : M - 1);

    // stage half0 (linear dest; source pre-swizzled)
#pragma unroll
    for (int p = 0; p < 8; ++p) {
        const int c = p * 256 + tid;          // chunk 0..2047
        const int row = c >> 4, c16 = c & 15;
        const char* src = (const char*)Bt + row * 512 + c16 * 16;
        __builtin_amdgcn_global_load_lds(
            (const __attribute__((address_space(1))) unsigned int*)(const void*)src,
            (__attribute__((address_space(3))) unsigned int*)(void*)((char*)Bs + c * 16),
            16, 0, 0);
    }

    // Ph A-frags (used by half0 only)
    frag_ab pa0[4], pa1[4];
#pragma unroll
    for (int ks = 0; ks < 4; ++ks) {
        const int kk = ks * 32 + kg;
        pa0[ks] = *(const frag_ab*)&Ph[ar0 * 128 + kk];
        pa1[ks] = *(const frag_ab*)&Ph[ar1 * 128 + kk];
    }

    f32x4 acc[2][8];
#pragma unroll
    for (int i = 0; i < 2; ++i)
#pragma unroll
        for (int j = 0; j < 8; ++j) acc[i][j] = (f32x4){0.f, 0.f, 0.f, 0.f};

    __syncthreads();
#pragma unroll
    for (int ks = 0; ks < 4; ++ks) {
        const int kb = ks * 64 + kg * 2;
#pragma unroll
        for (int nf = 0; nf < 8; ++nf) {
            const int r = nf * 16 + rl;
            const frag_ab bv = *(const frag_ab*)&Bs[r * 128 + ((kb ^ ((r & 7) << 4)) >> 1)];
            acc[0][nf] = __builtin_amdgcn_mfma_f32_16x16x32_bf16(pa0[ks], bv, acc[0][nf], 0, 0, 0);
            acc[1][nf] = __builtin_amdgcn_mfma_f32_16x16x32_bf16(pa1[ks], bv, acc[1][nf], 0, 0, 0);
        }
    }
    __syncthreads();

    // stage half1 + Xh A-frags (used by half1 only)
#pragma unroll
    for (int p = 0; p < 8; ++p) {
        const int c = p * 256 + tid;
        const int row = c >> 4, c16 = c & 15;
        const char* src = (const char*)Bt + row * 512 + 256 + c16 * 16;
        __builtin_amdgcn_global_load_lds(
            (const __attribute__((address_space(1))) unsigned int*)(const void*)src,
            (__attribute__((address_space(3))) unsigned int*)(void*)((char*)Bs + c * 16),
            16, 0, 0);
    }
    frag_ab xa0[4], xa1[4];
#pragma unroll
    for (int ks = 0; ks < 4; ++ks) {
        const int kk = ks * 32 + kg;
        xa0[ks] = *(const frag_ab*)&Xh[ar0 * 128 + kk];
        xa1[ks] = *(const frag_ab*)&Xh[ar1 * 128 + kk];
    }
    __syncthreads();
#pragma unroll
    for (int ks = 0; ks < 4; ++ks) {
        const int kb = ks * 64 + kg * 2;
#pragma unroll
        for (int nf = 0; nf < 8; ++nf) {
            const int r = nf * 16 + rl;
            const frag_ab bv = *(const frag_ab*)&Bs[r * 128 + ((kb ^ ((r & 7) << 4)) >> 1)];
            acc[0][nf] = __builtin_amdgcn_mfma_f32_16x16x32_bf16(xa0[ks], bv, acc[0][nf], 0, 0, 0);
            acc[1][nf] = __builtin_amdgcn_mfma_f32_16x16x32_bf16(xa1[ks], bv, acc[1][nf], 0, 0, 0);
        }
    }
    __syncthreads();

    const int rq = (lane >> 4) * 4;
    if (writeF32) {                                // last layer: fp32 direct stores
#pragma unroll
        for (int mf = 0; mf < 2; ++mf)
#pragma unroll
            for (int nf = 0; nf < 8; ++nf) {
                const int c = nf * 16 + rl;
                const float cv = cvec[c];
#pragma unroll
                for (int reg = 0; reg < 4; ++reg) {
                    const int r = rowbase + mf * 16 + rq + reg;
                    if (r < M) Xout[(size_t)r * 128 + c] = tanh_fast(acc[mf][nf][reg] + cv);
                }
            }
    } else {                                       // bf16 layers: LDS bounce, coalesced
#pragma unroll
        for (int mf = 0; mf < 2; ++mf)
#pragma unroll
            for (int nf = 0; nf < 8; ++nf) {
                const int c = nf * 16 + rl;
                const float cv = cvec[c];
#pragma unroll
                for (int reg = 0; reg < 4; ++reg) {
                    const int rloc = wid * 32 + mf * 16 + rq + reg;   // 0..127
                    Bs[rloc * 128 + (c ^ ((rloc & 7) << 3))] =
                        f2b(tanh_fast(acc[mf][nf][reg] + cv));
                }
            }
        __syncthreads();
#pragma unroll
        for (int k = 0; k < 8; ++k) {
            const int ci = k * 256 + tid;          // 16B-chunk index 0..2047
            const int row = ci >> 4, c8 = ci & 15;
            const int gr = blockIdx.x * 128 + row;
            if (gr < M) {
                const uint4 v = *(const uint4*)&Bs[row * 128 + ((c8 * 8) ^ ((row & 7) << 3))];
                *(uint4*)&XhOut[(size_t)gr * 128 + c8 * 8] = v;
            }
        }
    }
}

extern "C" void kernel_launch(void* const* d_in, const int* in_sizes, int n_in,
                              void* d_out, int out_size, void* d_ws, size_t ws_size,
                              hipStream_t stream) {
    const float* x    = (const float*)d_in[0];
    const int*   ei   = (const int*)d_in[1];
    const float* W    = (const float*)d_in[2];
    const float* b    = (const float*)d_in[3];
    const float* Wres = (const float*)d_in[4];
    const float* bres = (const float*)d_in[5];
    const int N = in_sizes[0] / 128;
    const int E = in_sizes[1] / 2;
    float* X = (float*)d_out;

    uint8_t* base = (uint8_t*)d_ws;
    size_t off = 0;
    auto carve = [&](size_t bytes) -> void* {
        void* p = base + off;
        off += (bytes + 255) & ~(size_t)255;
        return p;
    };
    const int NB = imin((N + WB - 1) / WB, MAXNB);
    const int L = NB * NBLK_A;

    u16*   Xh       = (u16*)carve((size_t)N * 128 * sizeof(u16));
    u16*   Ph       = (u16*)carve((size_t)N * 128 * sizeof(u16));
    u32*   pairs    = (u32*)carve((size_t)E * sizeof(u32));       // packed src|dlocal<<24
    uint2* csrW     = (uint2*)carve((size_t)E * sizeof(uint2));
    int*   csr_src  = (int*)carve((size_t)E * sizeof(int));
    int*   counts   = (int*)carve((size_t)L * sizeof(int));
    int*   rowptr   = (int*)carve(((size_t)N + 1) * sizeof(int));
    float* dinv     = (float*)carve((size_t)N * sizeof(float));
    u16*   Bt       = (u16*)carve(128 * 256 * sizeof(u16));
    float* cvec     = (float*)carve(128 * sizeof(float));
    int*   chunkSum = (int*)carve(4096);
    int*   chunkOff = (int*)carve(4096);

    const int EPB = (E + NBLK_A - 1) / NBLK_A;
    const int nChunks = (L + 2047) / 2048;

    k_bucket_count<<<NBLK_A, THREADS, 0, stream>>>(ei, E, EPB, NB, counts);
    k_chunk_sums<<<nChunks, THREADS, 0, stream>>>(counts, chunkSum, L);
    k_scan_offsets<<<1, 64, 0, stream>>>(chunkSum, chunkOff, nChunks);
    k_scan_write<<<nChunks, THREADS, 0, stream>>>(counts, chunkOff, L);
    k_bucket_scatter<<<NBLK_A, THREADS, 0, stream>>>(ei, E, EPB, NB, counts, pairs);
    k_build<<<NB, THREADS, 0, stream>>>(pairs, counts, rowptr, csr_src, dinv, N, NB, E);
    k_w2<<<64, THREADS, 0, stream>>>(W, Wres, b, bres, Bt, cvec);

    const long long n4 = (long long)N * 32;
    k_wfill_tanh<<<4096, THREADS, 0, stream>>>(csr_src, dinv, csrW, E, x, Xh, n4, 2048);

    for (int l = 0; l < 4; ++l) {
        k_agg<<<(N + 31) / 32, THREADS, 0, stream>>>(Xh, rowptr, csrW, Ph, N);
        k_gemm_mfma<<<(N + 127) / 128, THREADS, 0, stream>>>(Ph, Xh, Bt, cvec, X, Xh, N,
                                                             (l == 3) ? 1 : 0);
    }
}

// Round 14
// 407.090 us; speedup vs baseline: 1.0693x; 1.0693x over previous
//
#include <hip/hip_runtime.h>
#include <hip/hip_bf16.h>
#include <stdint.h>

#define THREADS 256
#define WB 256            // nodes per bucket
#define MAXNB 512         // max buckets
#define NBLK_A 512        // blocks in bucketing phase
#define ECAP 64           // staged edges per node (LDS)

typedef unsigned short u16;
typedef unsigned int u32;
using frag_ab = __attribute__((ext_vector_type(8))) short;   // 8 bf16 (4 VGPR)
using f32x4  = __attribute__((ext_vector_type(4))) float;    // 4 fp32 acc

static __host__ __device__ inline int imin(int a, int b) { return a < b ? a : b; }

static __device__ inline u16 f2b(float f) {               // f32 -> bf16 RNE
    u32 u = __builtin_bit_cast(u32, f);
    return (u16)((u + 0x7FFFu + ((u >> 16) & 1u)) >> 16);
}
static __device__ inline float b2f_lo(u32 v) { return __builtin_bit_cast(float, v << 16); }
static __device__ inline float b2f_hi(u32 v) { return __builtin_bit_cast(float, v & 0xFFFF0000u); }

// exact-formula tanh via HW exp2/rcp: rel err ~1e-6, correct at +-inf, NaN-free
static __device__ inline float tanh_fast(float x) {
    const float e = __builtin_amdgcn_exp2f(x * 2.8853900817779268f);  // 2*log2(e)
    return 1.0f - 2.0f * __builtin_amdgcn_rcpf(e + 1.0f);
}

static __device__ inline void fma8(float* a, float w, uint4 v) {
    a[0] = fmaf(w, b2f_lo(v.x), a[0]); a[1] = fmaf(w, b2f_hi(v.x), a[1]);
    a[2] = fmaf(w, b2f_lo(v.y), a[2]); a[3] = fmaf(w, b2f_hi(v.y), a[3]);
    a[4] = fmaf(w, b2f_lo(v.z), a[4]); a[5] = fmaf(w, b2f_hi(v.z), a[5]);
    a[6] = fmaf(w, b2f_lo(v.w), a[6]); a[7] = fmaf(w, b2f_hi(v.w), a[7]);
}

// per-block int64-vs-int32 detection (int64 => sampled high words all zero)
static __device__ inline bool detect64(const int* raw) {
    __shared__ int s64;
    if (threadIdx.x == 0) s64 = 1;
    __syncthreads();
    if (raw[2 * threadIdx.x + 1] != 0) s64 = 0;   // benign race
    __syncthreads();
    return s64 != 0;
}

// -- A1: per-block bucket histogram (blocks < NBLK_A) + fused W2 build (blocks >= NBLK_A) --
__global__ __launch_bounds__(256)
void k_bucket_count(const int* __restrict__ raw, int E, int EPB, int NB,
                    int* __restrict__ counts,
                    const float* __restrict__ W, const float* __restrict__ Wres,
                    const float* __restrict__ b, const float* __restrict__ bres,
                    u16* __restrict__ Bt, float* __restrict__ cvec) {
    __shared__ int cnt[MAXNB];
    const int t = threadIdx.x, blk = blockIdx.x;
    if (blk < NBLK_A) {
        const bool is64 = detect64(raw);
        for (int i = t; i < NB; i += THREADS) cnt[i] = 0;
        __syncthreads();
        const int e0 = blk * EPB, e1 = imin(E, e0 + EPB);
        for (int e = e0 + t; e < e1; e += THREADS) {
            const int d = is64 ? raw[2 * E + 2 * e] : raw[E + e];
            atomicAdd(&cnt[d >> 8], 1);   // WB = 256
        }
        __syncthreads();
        for (int i = t; i < NB; i += THREADS) counts[i * NBLK_A + blk] = cnt[i];
    } else {
        // W2 path: Bt pre-swizzled image of [W ; -(W@Wres)] col-major + cvec
        const int gid = (blk - NBLK_A) * THREADS + t;   // 0..16383
        const int i = gid >> 7, n = gid & 127;          // i = K row of W2, n = out col
        float s = 0.f;
#pragma unroll 8
        for (int k = 0; k < 128; ++k) s += W[i * 128 + k] * Wres[k * 128 + n];
        char* base = (char*)Bt;
        const int bh = i * 2;                           // byte within 256B half-row
        const int sb = ((bh & ~15) ^ ((n & 7) << 4)) | (bh & 15);
        *(u16*)(base + n * 512 + 256 + sb) = f2b(-s);              // W2n half
        *(u16*)(base + n * 512 + sb)       = f2b(W[i * 128 + n]);  // W half
        if (gid < 128) cvec[gid] = b[gid] - bres[gid];
    }
}

// ---------------- chunked exclusive scan over counts[L] (in-place) ----------------
__global__ void k_chunk_sums(const int* __restrict__ a, int* __restrict__ chunkSum, int L) {
    __shared__ int sm[THREADS];
    const int base = blockIdx.x * 2048 + threadIdx.x * 8;
    int s = 0;
#pragma unroll
    for (int i = 0; i < 8; ++i) { int idx = base + i; if (idx < L) s += a[idx]; }
    sm[threadIdx.x] = s;
    __syncthreads();
    for (int off = THREADS / 2; off > 0; off >>= 1) {
        if (threadIdx.x < off) sm[threadIdx.x] += sm[threadIdx.x + off];
        __syncthreads();
    }
    if (threadIdx.x == 0) chunkSum[blockIdx.x] = sm[0];
}

__global__ void k_scan_offsets(const int* __restrict__ chunkSum, int* __restrict__ chunkOff,
                               int nChunks) {
    if (blockIdx.x == 0 && threadIdx.x == 0) {
        int run = 0;
        for (int i = 0; i < nChunks; ++i) { chunkOff[i] = run; run += chunkSum[i]; }
    }
}

__global__ void k_scan_write(int* __restrict__ a, const int* __restrict__ chunkOff, int L) {
    __shared__ int sm[THREADS];
    const int tid = threadIdx.x;
    const int base = blockIdx.x * 2048 + tid * 8;
    int v[8]; int s = 0;
#pragma unroll
    for (int i = 0; i < 8; ++i) { int idx = base + i; v[i] = (idx < L) ? a[idx] : 0; s += v[i]; }
    const int mysum = s;
    sm[tid] = s;
    __syncthreads();
    for (int off = 1; off < THREADS; off <<= 1) {
        int t = (tid >= off) ? sm[tid - off] : 0;
        __syncthreads();
        sm[tid] += t;
        __syncthreads();
    }
    int run = chunkOff[blockIdx.x] + sm[tid] - mysum;  // exclusive prefix
#pragma unroll
    for (int i = 0; i < 8; ++i) {
        int idx = base + i;
        if (idx < L) { a[idx] = run; run += v[i]; }
    }
}

// -------- A3: scatter packed (src | dlocal<<24) into bucket regions (4B/edge) --------
__global__ __launch_bounds__(256)
void k_bucket_scatter(const int* __restrict__ raw, int E, int EPB, int NB,
                      const int* __restrict__ offs, u32* __restrict__ pairs) {
    const bool is64 = detect64(raw);
    __shared__ int cur[MAXNB];
    const int t = threadIdx.x, blk = blockIdx.x;
    for (int i = t; i < NB; i += THREADS) cur[i] = offs[i * NBLK_A + blk];
    __syncthreads();
    const int e0 = blk * EPB, e1 = imin(E, e0 + EPB);
    for (int e = e0 + t; e < e1; e += THREADS) {
        int s, d;
        if (is64) { s = raw[2 * e]; d = raw[2 * E + 2 * e]; }
        else      { s = raw[e];     d = raw[E + e]; }
        const int p = atomicAdd(&cur[d >> 8], 1);
        pairs[p] = (u32)s | ((u32)(d & 255) << 24);    // requires N < 2^24
    }
}

// ---- B: per-bucket CSR build (deg/dinv/rowptr/csr_src), direct node order ----
__global__ __launch_bounds__(256)
void k_build(const u32* __restrict__ pairs, const int* __restrict__ offs,
             int* __restrict__ rowptr, int* __restrict__ csr_src,
             float* __restrict__ dinv, int N, int NB, int E) {
    __shared__ int deg[WB];
    __shared__ int ptr[WB];
    __shared__ int cur[WB];
    const int k = blockIdx.x, t = threadIdx.x;
    const int base = offs[k * NBLK_A];
    const int end  = (k + 1 < NB) ? offs[(k + 1) * NBLK_A] : E;
    const int n0 = k * WB;
    deg[t] = 0;
    __syncthreads();
    for (int e = base + t; e < end; e += THREADS)
        atomicAdd(&deg[pairs[e] >> 24], 1);
    __syncthreads();
    const int dv = deg[t];
    if (n0 + t < N) dinv[n0 + t] = rsqrtf((float)dv + 1.0f);
    ptr[t] = dv;
    __syncthreads();
    for (int off = 1; off < THREADS; off <<= 1) {
        int v = (t >= off) ? ptr[t - off] : 0;
        __syncthreads();
        ptr[t] += v;
        __syncthreads();
    }
    const int excl = ptr[t] - dv;
    if (n0 + t < N) rowptr[n0 + t] = base + excl;
    if (k == NB - 1 && t == 0) rowptr[N] = E;
    cur[t] = base + excl;
    __syncthreads();
    for (int e = base + t; e < end; e += THREADS) {
        const u32 w = pairs[e];
        const int p = atomicAdd(&cur[w >> 24], 1);
        csr_src[p] = (int)(w & 0xFFFFFF);
    }
}

// ---- fused: csrW[e] = {src, dinv[src]}  (blocks < WFB)  +  Xh0 = bf16(tanh(x)) ----
__global__ void k_wfill_tanh(const int* __restrict__ csr_src, const float* __restrict__ dinv,
                             uint2* __restrict__ csrW, int E,
                             const float* __restrict__ x, u16* __restrict__ Xh,
                             long long n4, int WFB) {
    if ((int)blockIdx.x < WFB) {
        int i = blockIdx.x * blockDim.x + threadIdx.x;
        const int st = WFB * blockDim.x;
        for (; i < E; i += st) {
            const int s = csr_src[i];
            csrW[i] = make_uint2((u32)s, __builtin_bit_cast(u32, dinv[s]));
        }
    } else {
        long long i = (long long)(blockIdx.x - WFB) * blockDim.x + threadIdx.x;
        const long long st = (long long)(gridDim.x - WFB) * blockDim.x;
        for (; i < n4; i += st) {
            float4 v = ((const float4*)x)[i];
            u32 lo = f2b(tanh_fast(v.x)) | ((u32)f2b(tanh_fast(v.y)) << 16);
            u32 hi = f2b(tanh_fast(v.z)) | ((u32)f2b(tanh_fast(v.w)) << 16);
            ((uint2*)Xh)[i] = make_uint2(lo, hi);
        }
    }
}

// ------- Ph = bf16(dinv[d]*(Σ w_s·Xh[s] + dinv[d]·Xh[d])), quarter-wave per node -------
// round-12 body (proven 60.5us): LDS edge-index staging; quarter-local -> no syncs.
__global__ __launch_bounds__(256)
void k_agg(const u16* __restrict__ Xh, const int* __restrict__ rowptr,
           const uint2* __restrict__ csrW, u16* __restrict__ Ph, int N) {
    __shared__ uint2 cws[16][ECAP];            // 8 KB
    const int qid = threadIdx.x >> 4;          // 0..15 within block
    const int l16 = threadIdx.x & 15;
    const int node = blockIdx.x * 16 + qid;
    const bool valid = node < N;
    const int c8 = l16 * 8;
    int e0 = 0, e1 = 0;
    if (valid) { e0 = rowptr[node]; e1 = rowptr[node + 1]; }
    const int deg = e1 - e0;
    const int ns = deg < ECAP ? deg : ECAP;
    for (int j = l16; j < ns; j += 16)         // coalesced 128B index loads, all upfront
        cws[qid][j] = csrW[e0 + j];
    const float dn = rsqrtf((float)deg + 1.0f);
    float acc[8] = {0.f, 0.f, 0.f, 0.f, 0.f, 0.f, 0.f, 0.f};
    if (valid) {                               // self-loop term
        const uint4 v = *(const uint4*)&Xh[(size_t)node * 128 + c8];
        fma8(acc, dn, v);
    }
    int j = 0;
    for (; j + 3 < ns; j += 4) {
        const uint2 cw0 = cws[qid][j],     cw1 = cws[qid][j + 1];
        const uint2 cw2 = cws[qid][j + 2], cw3 = cws[qid][j + 3];
        const uint4 v0 = *(const uint4*)&Xh[(size_t)cw0.x * 128 + c8];
        const uint4 v1 = *(const uint4*)&Xh[(size_t)cw1.x * 128 + c8];
        const uint4 v2 = *(const uint4*)&Xh[(size_t)cw2.x * 128 + c8];
        const uint4 v3 = *(const uint4*)&Xh[(size_t)cw3.x * 128 + c8];
        fma8(acc, __builtin_bit_cast(float, cw0.y), v0);
        fma8(acc, __builtin_bit_cast(float, cw1.y), v1);
        fma8(acc, __builtin_bit_cast(float, cw2.y), v2);
        fma8(acc, __builtin_bit_cast(float, cw3.y), v3);
    }
    for (; j < ns; ++j) {
        const uint2 cw = cws[qid][j];
        const uint4 v = *(const uint4*)&Xh[(size_t)cw.x * 128 + c8];
        fma8(acc, __builtin_bit_cast(float, cw.y), v);
    }
    for (int e = e0 + ECAP; e < e1; ++e) {     // overflow fallback (deg > ECAP), rare
        const uint2 cw = csrW[e];
        const uint4 v = *(const uint4*)&Xh[(size_t)cw.x * 128 + c8];
        fma8(acc, __builtin_bit_cast(float, cw.y), v);
    }
    if (valid) {
        u32 w0 = (u32)f2b(acc[0] * dn) | ((u32)f2b(acc[1] * dn) << 16);
        u32 w1 = (u32)f2b(acc[2] * dn) | ((u32)f2b(acc[3] * dn) << 16);
        u32 w2 = (u32)f2b(acc[4] * dn) | ((u32)f2b(acc[5] * dn) << 16);
        u32 w3 = (u32)f2b(acc[6] * dn) | ((u32)f2b(acc[7] * dn) << 16);
        *(uint4*)&Ph[(size_t)node * 128 + c8] = make_uint4(w0, w1, w2, w3);
    }
}

// -------- Xh = bf16(tanh([Ph|Xh] @ Bt^T + cvec)); fp32 out on last layer ----
// split-K; Bt pre-swizzled in global -> staged LINEARLY via global_load_lds;
// per-half A-frags (half0 Ph only, half1 Xh only).
__global__ __launch_bounds__(256)
void k_gemm_mfma(const u16* __restrict__ Ph, const u16* __restrict__ Xh,
                 const u16* __restrict__ Bt, const float* __restrict__ cvec,
                 float* __restrict__ Xout, u16* __restrict__ XhOut, int M, int writeF32) {
    __shared__ u16 Bs[128 * 128];     // 32 KB
    const int tid = threadIdx.x;
    const int wid = tid >> 6, lane = tid & 63;
    const int rowbase = blockIdx.x * 128 + wid * 32;
    const int rl = lane & 15;
    const int kg = (lane >> 4) * 8;

    const int r0 = rowbase + rl;
    const size_t ar0 = (size_t)((r0      < M) ? r0      : M - 1);
    const size_t ar1 = (size_t)((r0 + 16 < M) ? r0 + 16 : M - 1);

    // stage half0 (linear dest; source pre-swizzled)
#pragma unroll
    for (int p = 0; p < 8; ++p) {
        const int c = p * 256 + tid;          // chunk 0..2047
        const int row = c >> 4, c16 = c & 15;
        const char* src = (const char*)Bt + row * 512 + c16 * 16;
        __builtin_amdgcn_global_load_lds(
            (const __attribute__((address_space(1))) unsigned int*)(const void*)src,
            (__attribute__((address_space(3))) unsigned int*)(void*)((char*)Bs + c * 16),
            16, 0, 0);
    }

    // Ph A-frags (used by half0 only)
    frag_ab pa0[4], pa1[4];
#pragma unroll
    for (int ks = 0; ks < 4; ++ks) {
        const int kk = ks * 32 + kg;
        pa0[ks] = *(const frag_ab*)&Ph[ar0 * 128 + kk];
        pa1[ks] = *(const frag_ab*)&Ph[ar1 * 128 + kk];
    }

    f32x4 acc[2][8];
#pragma unroll
    for (int i = 0; i < 2; ++i)
#pragma unroll
        for (int j = 0; j < 8; ++j) acc[i][j] = (f32x4){0.f, 0.f, 0.f, 0.f};

    __syncthreads();
#pragma unroll
    for (int ks = 0; ks < 4; ++ks) {
        const int kb = ks * 64 + kg * 2;
#pragma unroll
        for (int nf = 0; nf < 8; ++nf) {
            const int r = nf * 16 + rl;
            const frag_ab bv = *(const frag_ab*)&Bs[r * 128 + ((kb ^ ((r & 7) << 4)) >> 1)];
            acc[0][nf] = __builtin_amdgcn_mfma_f32_16x16x32_bf16(pa0[ks], bv, acc[0][nf], 0, 0, 0);
            acc[1][nf] = __builtin_amdgcn_mfma_f32_16x16x32_bf16(pa1[ks], bv, acc[1][nf], 0, 0, 0);
        }
    }
    __syncthreads();

    // stage half1 + Xh A-frags (used by half1 only)
#pragma unroll
    for (int p = 0; p < 8; ++p) {
        const int c = p * 256 + tid;
        const int row = c >> 4, c16 = c & 15;
        const char* src = (const char*)Bt + row * 512 + 256 + c16 * 16;
        __builtin_amdgcn_global_load_lds(
            (const __attribute__((address_space(1))) unsigned int*)(const void*)src,
            (__attribute__((address_space(3))) unsigned int*)(void*)((char*)Bs + c * 16),
            16, 0, 0);
    }
    frag_ab xa0[4], xa1[4];
#pragma unroll
    for (int ks = 0; ks < 4; ++ks) {
        const int kk = ks * 32 + kg;
        xa0[ks] = *(const frag_ab*)&Xh[ar0 * 128 + kk];
        xa1[ks] = *(const frag_ab*)&Xh[ar1 * 128 + kk];
    }
    __syncthreads();
#pragma unroll
    for (int ks = 0; ks < 4; ++ks) {
        const int kb = ks * 64 + kg * 2;
#pragma unroll
        for (int nf = 0; nf < 8; ++nf) {
            const int r = nf * 16 + rl;
            const frag_ab bv = *(const frag_ab*)&Bs[r * 128 + ((kb ^ ((r & 7) << 4)) >> 1)];
            acc[0][nf] = __builtin_amdgcn_mfma_f32_16x16x32_bf16(xa0[ks], bv, acc[0][nf], 0, 0, 0);
            acc[1][nf] = __builtin_amdgcn_mfma_f32_16x16x32_bf16(xa1[ks], bv, acc[1][nf], 0, 0, 0);
        }
    }
    __syncthreads();

    const int rq = (lane >> 4) * 4;
    if (writeF32) {                                // last layer: fp32 direct stores
#pragma unroll
        for (int mf = 0; mf < 2; ++mf)
#pragma unroll
            for (int nf = 0; nf < 8; ++nf) {
                const int c = nf * 16 + rl;
                const float cv = cvec[c];
#pragma unroll
                for (int reg = 0; reg < 4; ++reg) {
                    const int r = rowbase + mf * 16 + rq + reg;
                    if (r < M) Xout[(size_t)r * 128 + c] = tanh_fast(acc[mf][nf][reg] + cv);
                }
            }
    } else {                                       // bf16 layers: LDS bounce, coalesced
#pragma unroll
        for (int mf = 0; mf < 2; ++mf)
#pragma unroll
            for (int nf = 0; nf < 8; ++nf) {
                const int c = nf * 16 + rl;
                const float cv = cvec[c];
#pragma unroll
                for (int reg = 0; reg < 4; ++reg) {
                    const int rloc = wid * 32 + mf * 16 + rq + reg;   // 0..127
                    Bs[rloc * 128 + (c ^ ((rloc & 7) << 3))] =
                        f2b(tanh_fast(acc[mf][nf][reg] + cv));
                }
            }
        __syncthreads();
#pragma unroll
        for (int k = 0; k < 8; ++k) {
            const int ci = k * 256 + tid;          // 16B-chunk index 0..2047
            const int row = ci >> 4, c8 = ci & 15;
            const int gr = blockIdx.x * 128 + row;
            if (gr < M) {
                const uint4 v = *(const uint4*)&Bs[row * 128 + ((c8 * 8) ^ ((row & 7) << 3))];
                *(uint4*)&XhOut[(size_t)gr * 128 + c8 * 8] = v;
            }
        }
    }
}

extern "C" void kernel_launch(void* const* d_in, const int* in_sizes, int n_in,
                              void* d_out, int out_size, void* d_ws, size_t ws_size,
                              hipStream_t stream) {
    const float* x    = (const float*)d_in[0];
    const int*   ei   = (const int*)d_in[1];
    const float* W    = (const float*)d_in[2];
    const float* b    = (const float*)d_in[3];
    const float* Wres = (const float*)d_in[4];
    const float* bres = (const float*)d_in[5];
    const int N = in_sizes[0] / 128;
    const int E = in_sizes[1] / 2;
    float* X = (float*)d_out;

    uint8_t* base = (uint8_t*)d_ws;
    size_t off = 0;
    auto carve = [&](size_t bytes) -> void* {
        void* p = base + off;
        off += (bytes + 255) & ~(size_t)255;
        return p;
    };
    const int NB = imin((N + WB - 1) / WB, MAXNB);
    const int L = NB * NBLK_A;

    u16*   Xh       = (u16*)carve((size_t)N * 128 * sizeof(u16));
    u16*   Ph       = (u16*)carve((size_t)N * 128 * sizeof(u16));
    u32*   pairs    = (u32*)carve((size_t)E * sizeof(u32));       // packed src|dlocal<<24
    uint2* csrW     = (uint2*)carve((size_t)E * sizeof(uint2));
    int*   csr_src  = (int*)carve((size_t)E * sizeof(int));
    int*   counts   = (int*)carve((size_t)L * sizeof(int));
    int*   rowptr   = (int*)carve(((size_t)N + 1) * sizeof(int));
    float* dinv     = (float*)carve((size_t)N * sizeof(float));
    u16*   Bt       = (u16*)carve(128 * 256 * sizeof(u16));
    float* cvec     = (float*)carve(128 * sizeof(float));
    int*   chunkSum = (int*)carve(4096);
    int*   chunkOff = (int*)carve(4096);

    const int EPB = (E + NBLK_A - 1) / NBLK_A;
    const int nChunks = (L + 2047) / 2048;

    k_bucket_count<<<NBLK_A + 64, THREADS, 0, stream>>>(ei, E, EPB, NB, counts,
                                                        W, Wres, b, bres, Bt, cvec);
    k_chunk_sums<<<nChunks, THREADS, 0, stream>>>(counts, chunkSum, L);
    k_scan_offsets<<<1, 64, 0, stream>>>(chunkSum, chunkOff, nChunks);
    k_scan_write<<<nChunks, THREADS, 0, stream>>>(counts, chunkOff, L);
    k_bucket_scatter<<<NBLK_A, THREADS, 0, stream>>>(ei, E, EPB, NB, counts, pairs);
    k_build<<<NB, THREADS, 0, stream>>>(pairs, counts, rowptr, csr_src, dinv, N, NB, E);

    const long long n4 = (long long)N * 32;
    k_wfill_tanh<<<4096, THREADS, 0, stream>>>(csr_src, dinv, csrW, E, x, Xh, n4, 2048);

    for (int l = 0; l < 4; ++l) {
        k_agg<<<(N + 15) / 16, THREADS, 0, stream>>>(Xh, rowptr, csrW, Ph, N);
        k_gemm_mfma<<<(N + 127) / 128, THREADS, 0, stream>>>(Ph, Xh, Bt, cvec, X, Xh, N,
                                                             (l == 3) ? 1 : 0);
    }
}